// Round 1
// baseline (516.626 us; speedup 1.0000x reference)
//
#include <hip/hip_runtime.h>

// Problem constants (fixed by setup_inputs: B=16, Cin=Cout=64, H=W=224,
// K=3, pad=1, stride=1, PH=PW=32, version=3).
constexpr int B_ = 16, C_ = 64, H_ = 224, W_ = 224;
constexpr int PH_ = 32, PW_ = 32;
constexpr int PLANE  = H_ * W_;      // 50176
constexpr int PLANE4 = PLANE / 4;    // 12544 float4 per (b,c) plane
constexpr int ROW4   = W_ / 4;       // 56 float4 per row
constexpr unsigned TOTAL4 = (unsigned)B_ * C_ * PLANE4;  // 12,845,056

constexpr int CONV_BLOCKS = 256;     // 16 batches x 16 cout-groups (4 couts each)
constexpr int COPY_BLOCKS = 1792;    // 28 exact iterations of the grid-stride copy
constexpr int THREADS = 256;

// Conv over one batch's 32x32 patch for 4 consecutive couts.
// Each thread: tx = ox (0..31), ty = 0..7, handles oy = ty + 8r (r=0..3).
// EDGE=true adds lower-bound zero-pad guards (only needed when y==0 or x==0;
// upper bounds can never be exceeded since y,x <= 191).
template <bool EDGE>
__device__ __forceinline__ void conv_patch(
    int b, int co0, int tid, int y, int x,
    const float* __restrict__ in, const float* __restrict__ bias,
    float* __restrict__ out, const float4* wlds)
{
    const int tx = tid & 31;
    const int ty = tid >> 5;
    const float* inb = in + (size_t)b * C_ * PLANE;

    float acc[4][4];
#pragma unroll
    for (int r = 0; r < 4; ++r)
#pragma unroll
        for (int j = 0; j < 4; ++j) acc[r][j] = 0.f;

    const int c0 = x + tx - 1;  // leftmost input col this thread touches

#pragma unroll 1
    for (int cin = 0; cin < C_; ++cin) {
        const float* ip = inb + cin * PLANE;
        float4 w[9];
#pragma unroll
        for (int t = 0; t < 9; ++t) w[t] = wlds[cin * 9 + t];  // LDS broadcast

#pragma unroll
        for (int r = 0; r < 4; ++r) {
            const int oy = ty + r * 8;
            const int r0 = y + oy - 1;
#pragma unroll
            for (int dy = 0; dy < 3; ++dy) {
                const int ri = r0 + dy;
                const float* rowp = ip + ri * W_;
#pragma unroll
                for (int dx = 0; dx < 3; ++dx) {
                    const int ci = c0 + dx;
                    float v;
                    if (EDGE) {
                        v = 0.f;
                        if (ri >= 0 && ci >= 0) v = rowp[ci];
                    } else {
                        v = rowp[ci];
                    }
                    const float4 wv = w[dy * 3 + dx];
                    acc[r][0] += v * wv.x;
                    acc[r][1] += v * wv.y;
                    acc[r][2] += v * wv.z;
                    acc[r][3] += v * wv.w;
                }
            }
        }
    }

    float bs[4];
#pragma unroll
    for (int j = 0; j < 4; ++j) bs[j] = bias[co0 + j];

#pragma unroll
    for (int r = 0; r < 4; ++r) {
        const int row = y + ty + r * 8;
#pragma unroll
        for (int j = 0; j < 4; ++j) {
            out[(size_t)(b * C_ + co0 + j) * PLANE + row * W_ + (x + tx)] =
                acc[r][j] + bs[j];
        }
    }
}

__global__ __launch_bounds__(THREADS) void inc_conv_fused(
    const float* __restrict__ in, const float* __restrict__ wt,
    const float* __restrict__ bias, const float* __restrict__ stale,
    const int* __restrict__ loc, float* __restrict__ out)
{
    __shared__ float4 wlds[C_ * 9];   // [cin*9 + tap] -> weights for 4 couts
    __shared__ int    locs[2 * B_];

    const int tid = threadIdx.x;
    const int bid = blockIdx.x;

    if (bid < CONV_BLOCKS) {
        // ---------------- conv blocks: write exactly the patch region -------
        const int b   = bid >> 4;
        const int co0 = (bid & 15) * 4;

        // Stage weights: w[co][cin][kh][kw] -> wlds[cin*9+tap] = {co0..co0+3}
        for (int idx = tid; idx < C_ * 9; idx += THREADS) {
            const int cin = idx / 9;
            const int tap = idx - cin * 9;
            float4 wv;
            wv.x = wt[(co0 + 0) * C_ * 9 + cin * 9 + tap];
            wv.y = wt[(co0 + 1) * C_ * 9 + cin * 9 + tap];
            wv.z = wt[(co0 + 2) * C_ * 9 + cin * 9 + tap];
            wv.w = wt[(co0 + 3) * C_ * 9 + cin * 9 + tap];
            wlds[idx] = wv;
        }
        __syncthreads();

        const int y = loc[2 * b], x = loc[2 * b + 1];
        if (y > 0 && x > 0)
            conv_patch<false>(b, co0, tid, y, x, in, bias, out, wlds);
        else
            conv_patch<true>(b, co0, tid, y, x, in, bias, out, wlds);
    } else {
        // ---------------- copy blocks: everything EXCEPT the patch region ---
        if (tid < 2 * B_) locs[tid] = loc[tid];
        __syncthreads();

        const float4* src4 = (const float4*)stale;
        float4*       dst4 = (float4*)out;
        const unsigned stride = (unsigned)COPY_BLOCKS * THREADS;
        unsigned i = (unsigned)(bid - CONV_BLOCKS) * THREADS + tid;

        for (; i < TOTAL4; i += stride) {
            const float4 v = src4[i];
            const unsigned plane = i / PLANE4;           // magic-mul
            const unsigned p     = i - plane * PLANE4;
            const unsigned b     = plane >> 6;           // 64 planes per batch
            const unsigned h     = p / ROW4;
            const unsigned w4    = p - h * ROW4;
            const unsigned yy = (unsigned)locs[2 * b];
            const unsigned xx = (unsigned)locs[2 * b + 1];
            const unsigned cc0 = w4 * 4;

            const bool inrow = (h - yy) < (unsigned)PH_;
            const bool ovl = inrow & (cc0 + 3 >= xx) & (cc0 <= xx + (PW_ - 1));
            if (!ovl) {
                dst4[i] = v;                 // fast path: whole float4
            } else {
                // partial/full overlap with patch cols: store only outside cols
                const float* vf = (const float*)&v;
                float* dstf = out + (size_t)i * 4;
#pragma unroll
                for (int k = 0; k < 4; ++k) {
                    const unsigned c = cc0 + k;
                    if ((c - xx) >= (unsigned)PW_) dstf[k] = vf[k];
                }
            }
        }
    }
}

extern "C" void kernel_launch(void* const* d_in, const int* in_sizes, int n_in,
                              void* d_out, int out_size, void* d_ws, size_t ws_size,
                              hipStream_t stream) {
    const float* in   = (const float*)d_in[0];  // (16,64,224,224) fp32
    const float* wt   = (const float*)d_in[1];  // (64,64,3,3) fp32
    const float* bias = (const float*)d_in[2];  // (64,) fp32
    const float* st   = (const float*)d_in[3];  // (16,64,224,224) fp32 stale out
    const int*   loc  = (const int*)d_in[4];    // (16,2) int32 (y,x)
    float* out = (float*)d_out;

    inc_conv_fused<<<dim3(CONV_BLOCKS + COPY_BLOCKS), dim3(THREADS), 0, stream>>>(
        in, wt, bias, st, loc, out);
}